// Round 12
// baseline (272.723 us; speedup 1.0000x reference)
//
#include <hip/hip_runtime.h>

// Problem constants
#define BATCH   2
#define S_LEN   4096
#define D_MODEL 768
#define NH      12
#define HDIM    64
#define MROWS   (BATCH * S_LEN)   // 8192
#define QBLK    128
#define KVBLK   64
#define NT      (S_LEN / KVBLK)   // 64
#define NXB     (MROWS * D_MODEL / 4 / 256)   // 6144 conv blocks
#define NTW     2304                          // 24*24*4 trans_w blocks
#define LOG2E   1.4426950408889634f

typedef float f32x4  __attribute__((ext_vector_type(4)));
typedef float f32x16 __attribute__((ext_vector_type(16)));
typedef short bf16x8 __attribute__((ext_vector_type(8)));

#if __has_builtin(__builtin_amdgcn_exp2f)
#define EXP2(x) __builtin_amdgcn_exp2f(x)
#else
#define EXP2(x) exp2f(x)
#endif

static __device__ __forceinline__ unsigned short f2bf(float f) {
  union { float f; unsigned u; } v; v.f = f;
  unsigned r = v.u + 0x7fffu + ((v.u >> 16) & 1u);
  return (unsigned short)(r >> 16);
}

static __device__ __forceinline__ unsigned cvtpk(float lo, float hi) {
  unsigned r;
  asm("v_cvt_pk_bf16_f32 %0, %1, %2" : "=v"(r) : "v"(lo), "v"(hi));
  return r;
}

// async global->LDS, 16B per lane (dest must be wave-uniform base + lane*16)
typedef __attribute__((address_space(1))) const unsigned int as1_cuint;
typedef __attribute__((address_space(3))) unsigned int as3_uint;
static __device__ __forceinline__ void gload_lds16(const unsigned short* g,
                                                   unsigned short* l) {
  __builtin_amdgcn_global_load_lds((as1_cuint*)g, (as3_uint*)l, 16, 0, 0);
}

// Build PV A-fragment from 8 P regs (layout verified R2).
template <int BASE>
static __device__ __forceinline__ bf16x8 pack_frag(const f32x16& s) {
  unsigned a0 = cvtpk(s[BASE + 0], s[BASE + 1]);
  unsigned b0 = cvtpk(s[BASE + 4], s[BASE + 5]);
  asm("v_permlane32_swap_b32 %0, %1" : "+v"(a0), "+v"(b0));
  unsigned a1 = cvtpk(s[BASE + 2], s[BASE + 3]);
  unsigned b1 = cvtpk(s[BASE + 6], s[BASE + 7]);
  asm("v_permlane32_swap_b32 %0, %1" : "+v"(a1), "+v"(b1));
  union { unsigned w[4]; bf16x8 v; } u;
  u.w[0] = a0; u.w[1] = a1; u.w[2] = b0; u.w[3] = b1;
  return u.v;
}

#define Z16 {0.f,0.f,0.f,0.f,0.f,0.f,0.f,0.f,0.f,0.f,0.f,0.f,0.f,0.f,0.f,0.f}

// ---------------------------------------------------------------- fused prepass
// blocks [0, NXB)          : X -> bf16 (conv)
// block  NXB               : mask -> madd + allones flag
// blocks (NXB, NXB+NTW]    : W[k][n] fp32 -> T[n][k] bf16 (transpose), 4 weights
__global__ __launch_bounds__(256) void prepass(
    const float* __restrict__ X, unsigned short* __restrict__ Xb,
    const float* __restrict__ mask, float* __restrict__ madd, int* __restrict__ flag,
    const float* __restrict__ W0, const float* __restrict__ W1,
    const float* __restrict__ W2, const float* __restrict__ W3,
    unsigned short* __restrict__ T0, unsigned short* __restrict__ T1,
    unsigned short* __restrict__ T2, unsigned short* __restrict__ T3) {
  __shared__ float tile[32][33];
  __shared__ int ok[4];
  int bid = blockIdx.x;
  int t = threadIdx.x;
  if (bid < NXB) {
    int i = bid * 256 + t;
    float4 v = ((const float4*)X)[i];
    ushort4 o;
    o.x = f2bf(v.x); o.y = f2bf(v.y); o.z = f2bf(v.z); o.w = f2bf(v.w);
    ((ushort4*)Xb)[i] = o;
    return;
  }
  if (bid == NXB) {
    int all1 = 1;
    #pragma unroll
    for (int i = 0; i < MROWS / 256; ++i) {
      int idx = i * 256 + t;
      float m = mask[idx];
      madd[idx] = (-1e6f * LOG2E) * (1.0f - m);
      all1 &= (m == 1.0f);
    }
    all1 = __all(all1) ? 1 : 0;
    if ((t & 63) == 0) ok[t >> 6] = all1;
    __syncthreads();
    if (t == 0) *flag = ok[0] & ok[1] & ok[2] & ok[3];
    return;
  }
  // trans_w region
  int w2 = bid - (NXB + 1);          // 0..2303
  int zz = w2 / 576;
  int r = w2 - zz * 576;
  int bxi = r % 24, byi = r / 24;
  const float* W; unsigned short* T;
  if (zz == 0) { W = W0; T = T0; }
  else if (zz == 1) { W = W1; T = T1; }
  else if (zz == 2) { W = W2; T = T2; }
  else { W = W3; T = T3; }
  int tx = t & 31, ty = t >> 5;
  int bx = bxi * 32, by = byi * 32;
  #pragma unroll
  for (int i = ty; i < 32; i += 8) tile[i][tx] = W[(size_t)(by + i) * D_MODEL + bx + tx];
  __syncthreads();
  #pragma unroll
  for (int i = ty; i < 32; i += 8)
    T[(size_t)(bx + i) * D_MODEL + by + tx] = f2bf(tile[tx][i]);
}

// ---------------------------------------------------------------- QKV GEMM
// m97 structure: 128x128 tile, 4 waves x (64x64), BK=64, global_load_lds x16.
__global__ __launch_bounds__(256) void qkv_gemm(
    const unsigned short* __restrict__ Xb,
    const unsigned short* __restrict__ Wqt, const unsigned short* __restrict__ Wkt,
    const unsigned short* __restrict__ Wvt,
    const float* __restrict__ bq, const float* __restrict__ bk, const float* __restrict__ bv,
    unsigned short* __restrict__ Qo, unsigned short* __restrict__ Ko,
    unsigned short* __restrict__ Vto) {
  __shared__ unsigned short As[128 * 64];   // linear [128][64]
  __shared__ unsigned short Bs[128 * 64];
  int zz = blockIdx.z;
  const unsigned short* Wt = zz == 0 ? Wqt : (zz == 1 ? Wkt : Wvt);
  const float* bias = zz == 0 ? bq : (zz == 1 ? bk : bv);
  int tid = threadIdx.x;
  int w = tid >> 6, lane = tid & 63, lr = lane & 15, lg = lane >> 4;
  int wr = w >> 1, wc = w & 1;
  int mb = blockIdx.x * 128, nb = blockIdx.y * 128;
  const unsigned short* Ag = Xb + (size_t)(mb + (tid >> 3)) * D_MODEL + (tid & 7) * 8;
  const unsigned short* Bg = Wt + (size_t)(nb + (tid >> 3)) * D_MODEL + (tid & 7) * 8;
  unsigned short* Al = As + (size_t)tid * 8;
  unsigned short* Bl = Bs + (size_t)tid * 8;
  f32x4 acc[4][4];
  #pragma unroll
  for (int m = 0; m < 4; ++m)
    #pragma unroll
    for (int n = 0; n < 4; ++n) acc[m][n] = (f32x4){0.f, 0.f, 0.f, 0.f};
  for (int kb = 0; kb < D_MODEL / 64; ++kb) {
    __syncthreads();
    #pragma unroll
    for (int i = 0; i < 4; ++i) {
      gload_lds16(Ag + (size_t)(i * 32) * D_MODEL + kb * 64, Al + i * 2048);
      gload_lds16(Bg + (size_t)(i * 32) * D_MODEL + kb * 64, Bl + i * 2048);
    }
    __syncthreads();   // compiler inserts vmcnt(0) drain
    #pragma unroll
    for (int kk = 0; kk < 2; ++kk) {
      bf16x8 af[4], bfv[4];
      #pragma unroll
      for (int m = 0; m < 4; ++m)
        af[m] = *(const bf16x8*)(As + (wr * 64 + m * 16 + lr) * 64 + kk * 32 + lg * 8);
      #pragma unroll
      for (int n = 0; n < 4; ++n)
        bfv[n] = *(const bf16x8*)(Bs + (wc * 64 + n * 16 + lr) * 64 + kk * 32 + lg * 8);
      #pragma unroll
      for (int m = 0; m < 4; ++m)
        #pragma unroll
        for (int n = 0; n < 4; ++n)
          acc[m][n] = __builtin_amdgcn_mfma_f32_16x16x32_bf16(af[m], bfv[n], acc[m][n], 0, 0, 0);
    }
  }
  #pragma unroll
  for (int n = 0; n < 4; ++n) {
    int nc = nb + wc * 64 + n * 16 + lr;
    float bia = bias[nc];
    int h = nc >> 6, hd = nc & 63;
    #pragma unroll
    for (int m = 0; m < 4; ++m) {
      #pragma unroll
      for (int r = 0; r < 4; ++r) {
        int mr = mb + wr * 64 + m * 16 + lg * 4 + r;
        int b = mr >> 12, s = mr & 4095;
        float val = acc[m][n][r] + bia;
        if (zz == 0)
          Qo[((size_t)(b * NH + h) * S_LEN + s) * HDIM + hd] = f2bf(val * 0.125f * LOG2E);
        else if (zz == 1)
          Ko[((size_t)(b * NH + h) * S_LEN + s) * HDIM + hd] = f2bf(val);
        else
          Vto[((size_t)(b * NH + h) * HDIM + hd) * S_LEN + s] = f2bf(val);
      }
    }
  }
}

// ---------------------------------------------------------------- attention
// 4 waves x 32 q-rows (QBLK=128). Double-buffered LDS K/V staged via
// global_load_lds (async, linear dest) with XOR-swizzled per-lane global
// source; reads apply the same involution (granule ^= row&7). One barrier
// per tile (vmcnt drain). XCD chunk swizzle. No max tracking (bounded
// scores; masked -> exp2(-1.4e6)=0).
__global__ __launch_bounds__(256) void attn_kernel(
    const unsigned short* __restrict__ Q, const unsigned short* __restrict__ K,
    const unsigned short* __restrict__ Vt, const float* __restrict__ madd,
    const int* __restrict__ allones_p, unsigned short* __restrict__ Ctx) {
  __shared__ unsigned short Ks[2][64][64];   // linear; content granule-swizzled
  __shared__ unsigned short Vs[2][64][64];
  int lin = blockIdx.x;                       // 0..767
  int wg = (lin & 7) * 96 + (lin >> 3);       // bijective (768 % 8 == 0)
  int qb = wg & 31, bh = wg >> 5;
  int b = bh / NH, h = bh % NH;
  int tid = threadIdx.x;
  int w = tid >> 6, lane = tid & 63;
  int lq = lane & 31, hi = lane >> 5;
  const unsigned short* Qb = Q + (size_t)bh * S_LEN * HDIM;
  const unsigned short* Kb = K + (size_t)bh * S_LEN * HDIM;
  const unsigned short* Vb = Vt + (size_t)bh * HDIM * S_LEN;
  const float* maddb = madd + (size_t)b * S_LEN;
  const int allones = *allones_p;

  int qrow = qb * QBLK + w * 32 + lq;
  bf16x8 qf0 = *(const bf16x8*)(Qb + (size_t)qrow * HDIM + 0 * 16 + hi * 8);
  bf16x8 qf1 = *(const bf16x8*)(Qb + (size_t)qrow * HDIM + 1 * 16 + hi * 8);
  bf16x8 qf2 = *(const bf16x8*)(Qb + (size_t)qrow * HDIM + 2 * 16 + hi * 8);
  bf16x8 qf3 = *(const bf16x8*)(Qb + (size_t)qrow * HDIM + 3 * 16 + hi * 8);

  f32x16 acc0 = Z16, acc1 = Z16;
  float l_run = 0.f;

  // staging: slot s covers LDS bytes [s*16, s*16+16); row = s>>3, granule = s&7.
  // global source granule = (s&7) ^ ((s>>3)&7)  (involution; 128B-chunk perm,
  // coalescing preserved). Thread stages slots tid and tid+256.
  int r0 = tid >> 3;
  int g0 = (tid & 7) ^ (r0 & 7);
  int r1 = (tid + 256) >> 3;
  int g1 = (tid & 7) ^ (r1 & 7);
  const unsigned short* kg0 = Kb + (size_t)r0 * HDIM + g0 * 8;
  const unsigned short* kg1 = Kb + (size_t)r1 * HDIM + g1 * 8;
  const unsigned short* vg0 = Vb + (size_t)r0 * S_LEN + g0 * 8;
  const unsigned short* vg1 = Vb + (size_t)r1 * S_LEN + g1 * 8;

  // prologue: stage tile 0 into buffer 0
  {
    unsigned short* kd = &Ks[0][0][0] + tid * 8;
    unsigned short* vd = &Vs[0][0][0] + tid * 8;
    gload_lds16(kg0, kd);
    gload_lds16(kg1, kd + 2048);
    gload_lds16(vg0, vd);
    gload_lds16(vg1, vd + 2048);
  }
  __syncthreads();

  for (int t = 0; t < NT; ++t) {
    int cur = t & 1;
    int kbase = t * KVBLK;
    // ---- issue next tile's async loads EARLY (land during compute)
    if (t + 1 < NT) {
      int off = kbase + KVBLK;
      unsigned short* kd = &Ks[cur ^ 1][0][0] + tid * 8;
      unsigned short* vd = &Vs[cur ^ 1][0][0] + tid * 8;
      gload_lds16(kg0 + (size_t)off * HDIM, kd);
      gload_lds16(kg1 + (size_t)off * HDIM, kd + 2048);
      gload_lds16(vg0 + off, vd);
      gload_lds16(vg1 + off, vd + 2048);
    }
    // ---- S^T[k][q] = K . Q^T  (granule-swizzled reads)
    f32x16 s0 = Z16, s1 = Z16;
    #pragma unroll
    for (int c = 0; c < 4; ++c) {
      int gq = (((c << 1) | hi) ^ (lq & 7)) * 8;
      bf16x8 kf0 = *(const bf16x8*)(&Ks[cur][lq][gq]);
      bf16x8 kf1 = *(const bf16x8*)(&Ks[cur][32 + lq][gq]);
      bf16x8 qf = c == 0 ? qf0 : (c == 1 ? qf1 : (c == 2 ? qf2 : qf3));
      s0 = __builtin_amdgcn_mfma_f32_32x32x16_bf16(kf0, qf, s0, 0, 0, 0);
      s1 = __builtin_amdgcn_mfma_f32_32x32x16_bf16(kf1, qf, s1, 0, 0, 0);
    }
    // ---- mask (skipped when all-ones; uniform branch)
    if (!allones) {
      #pragma unroll
      for (int g = 0; g < 4; ++g) {
        float4 m0 = *(const float4*)(maddb + kbase + g * 8 + hi * 4);
        float4 m1 = *(const float4*)(maddb + kbase + 32 + g * 8 + hi * 4);
        s0[g * 4 + 0] += m0.x; s0[g * 4 + 1] += m0.y;
        s0[g * 4 + 2] += m0.z; s0[g * 4 + 3] += m0.w;
        s1[g * 4 + 0] += m1.x; s1[g * 4 + 1] += m1.y;
        s1[g * 4 + 2] += m1.z; s1[g * 4 + 3] += m1.w;
      }
    }
    // ---- p = exp2(s), row sums (no max subtraction)
    float psA = 0.f, psB = 0.f, psC = 0.f, psD = 0.f;
    #pragma unroll
    for (int r = 0; r < 4; ++r) {
      s0[r]      = EXP2(s0[r]);      psA += s0[r];
      s0[r + 4]  = EXP2(s0[r + 4]);  psB += s0[r + 4];
      s0[r + 8]  = EXP2(s0[r + 8]);  psC += s0[r + 8];
      s0[r + 12] = EXP2(s0[r + 12]); psD += s0[r + 12];
    }
    #pragma unroll
    for (int r = 0; r < 4; ++r) {
      s1[r]      = EXP2(s1[r]);      psA += s1[r];
      s1[r + 4]  = EXP2(s1[r + 4]);  psB += s1[r + 4];
      s1[r + 8]  = EXP2(s1[r + 8]);  psC += s1[r + 8];
      s1[r + 12] = EXP2(s1[r + 12]); psD += s1[r + 12];
    }
    float psum = (psA + psB) + (psC + psD);
    psum += __shfl_xor(psum, 32, 64);
    l_run += psum;
    // ---- pack P and PV (granule-swizzled V reads)
    bf16x8 pa0 = pack_frag<0>(s0);
    bf16x8 pa1 = pack_frag<8>(s0);
    bf16x8 pa2 = pack_frag<0>(s1);
    bf16x8 pa3 = pack_frag<8>(s1);
    #pragma unroll
    for (int c = 0; c < 4; ++c) {
      int gq = (((c << 1) | hi) ^ (lq & 7)) * 8;
      bf16x8 pa = c == 0 ? pa0 : (c == 1 ? pa1 : (c == 2 ? pa2 : pa3));
      bf16x8 vf0 = *(const bf16x8*)(&Vs[cur][lq][gq]);
      bf16x8 vf1 = *(const bf16x8*)(&Vs[cur][32 + lq][gq]);
      acc0 = __builtin_amdgcn_mfma_f32_32x32x16_bf16(pa, vf0, acc0, 0, 0, 0);
      acc1 = __builtin_amdgcn_mfma_f32_32x32x16_bf16(pa, vf1, acc1, 0, 0, 0);
    }
    // ---- one barrier per tile: drains async loads + releases cur buffer
    if (t + 1 < NT) __syncthreads();
  }
  // ---- epilogue
  #pragma unroll
  for (int r = 0; r < 16; ++r) {
    int qr = (r & 3) + 8 * (r >> 2) + 4 * hi;
    float lv = __shfl(l_run, qr, 64);
    float rl = 1.0f / lv;
    int qglob = qb * QBLK + w * 32 + qr;
    size_t base = ((size_t)(b * S_LEN + qglob)) * D_MODEL + h * HDIM;
    Ctx[base + lq]      = f2bf(acc0[r] * rl);
    Ctx[base + 32 + lq] = f2bf(acc1[r] * rl);
  }
}

// ---------------------------------------------------------------- out proj
__global__ __launch_bounds__(256) void out_gemm(
    const unsigned short* __restrict__ Ctx, const unsigned short* __restrict__ Wot,
    const float* __restrict__ bo, float* __restrict__ Out) {
  __shared__ unsigned short As[128 * 64];
  __shared__ unsigned short Bs[128 * 64];
  int tid = threadIdx.x;
  int w = tid >> 6, lane = tid & 63, lr = lane & 15, lg = lane >> 4;
  int wr = w >> 1, wc = w & 1;
  int mb = blockIdx.x * 128, nb = blockIdx.y * 128;
  const unsigned short* Ag = Ctx + (size_t)(mb + (tid >> 3)) * D_MODEL + (tid & 7) * 8;
  const unsigned short* Bg = Wot + (size_t)(nb + (tid >> 3)) * D_MODEL + (tid & 7) * 8;
  unsigned short* Al = As + (size_t)tid * 8;
  unsigned short* Bl = Bs + (size_t)tid * 8;
  f32x4 acc[4][4];
  #pragma unroll
  for (int m = 0; m < 4; ++m)
    #pragma unroll
    for (int n = 0; n < 4; ++n) acc[m][n] = (f32x4){0.f, 0.f, 0.f, 0.f};
  for (int kb = 0; kb < D_MODEL / 64; ++kb) {
    __syncthreads();
    #pragma unroll
    for (int i = 0; i < 4; ++i) {
      gload_lds16(Ag + (size_t)(i * 32) * D_MODEL + kb * 64, Al + i * 2048);
      gload_lds16(Bg + (size_t)(i * 32) * D_MODEL + kb * 64, Bl + i * 2048);
    }
    __syncthreads();
    #pragma unroll
    for (int kk = 0; kk < 2; ++kk) {
      bf16x8 af[4], bfv[4];
      #pragma unroll
      for (int m = 0; m < 4; ++m)
        af[m] = *(const bf16x8*)(As + (wr * 64 + m * 16 + lr) * 64 + kk * 32 + lg * 8);
      #pragma unroll
      for (int n = 0; n < 4; ++n)
        bfv[n] = *(const bf16x8*)(Bs + (wc * 64 + n * 16 + lr) * 64 + kk * 32 + lg * 8);
      #pragma unroll
      for (int m = 0; m < 4; ++m)
        #pragma unroll
        for (int n = 0; n < 4; ++n)
          acc[m][n] = __builtin_amdgcn_mfma_f32_16x16x32_bf16(af[m], bfv[n], acc[m][n], 0, 0, 0);
    }
  }
  #pragma unroll
  for (int n = 0; n < 4; ++n) {
    int nc = nb + wc * 64 + n * 16 + lr;
    float bia = bo[nc];
    #pragma unroll
    for (int m = 0; m < 4; ++m) {
      #pragma unroll
      for (int r = 0; r < 4; ++r) {
        int mr = mb + wr * 64 + m * 16 + lg * 4 + r;
        Out[(size_t)mr * D_MODEL + nc] = acc[m][n][r] + bia;
      }
    }
  }
}

// ---------------------------------------------------------------- launch

extern "C" void kernel_launch(void* const* d_in, const int* in_sizes, int n_in,
                              void* d_out, int out_size, void* d_ws, size_t ws_size,
                              hipStream_t stream) {
  const float* X    = (const float*)d_in[0];
  const float* mask = (const float*)d_in[1];
  const float* Wq   = (const float*)d_in[2];
  const float* bq   = (const float*)d_in[3];
  const float* Wk   = (const float*)d_in[4];
  const float* bk   = (const float*)d_in[5];
  const float* Wv   = (const float*)d_in[6];
  const float* bv   = (const float*)d_in[7];
  const float* Wo   = (const float*)d_in[8];
  const float* bo   = (const float*)d_in[9];
  float* out = (float*)d_out;
  char* ws = (char*)d_ws;

  const size_t XB_OFF   = 0;
  const size_t WQT_OFF  = 12582912;
  const size_t WKT_OFF  = WQT_OFF + 1179648;
  const size_t WVT_OFF  = WKT_OFF + 1179648;
  const size_t WOT_OFF  = WVT_OFF + 1179648;
  const size_t Q_OFF    = WOT_OFF + 1179648;
  const size_t K_OFF    = Q_OFF + 12582912;
  const size_t VT_OFF   = K_OFF + 12582912;
  const size_t CTX_OFF  = VT_OFF + 12582912;
  const size_t MADD_OFF = CTX_OFF + 12582912;
  const size_t FLAG_OFF = MADD_OFF + MROWS * 4;

  unsigned short* Xb  = (unsigned short*)(ws + XB_OFF);
  unsigned short* Wqt = (unsigned short*)(ws + WQT_OFF);
  unsigned short* Wkt = (unsigned short*)(ws + WKT_OFF);
  unsigned short* Wvt = (unsigned short*)(ws + WVT_OFF);
  unsigned short* Wot = (unsigned short*)(ws + WOT_OFF);
  unsigned short* Qw  = (unsigned short*)(ws + Q_OFF);
  unsigned short* Kw  = (unsigned short*)(ws + K_OFF);
  unsigned short* Vtw = (unsigned short*)(ws + VT_OFF);
  unsigned short* Ctx = (unsigned short*)(ws + CTX_OFF);
  float* madd = (float*)(ws + MADD_OFF);
  int* flag   = (int*)(ws + FLAG_OFF);

  prepass<<<dim3(NXB + 1 + NTW), 256, 0, stream>>>(
      X, Xb, mask, madd, flag, Wq, Wk, Wv, Wo, Wqt, Wkt, Wvt, Wot);
  qkv_gemm<<<dim3(MROWS / 128, D_MODEL / 128, 3), 256, 0, stream>>>(
      Xb, Wqt, Wkt, Wvt, bq, bk, bv, Qw, Kw, Vtw);
  attn_kernel<<<dim3((S_LEN / QBLK) * (BATCH * NH)), 256, 0, stream>>>(
      Qw, Kw, Vtw, madd, flag, Ctx);
  out_gemm<<<dim3(MROWS / 128, D_MODEL / 128), 256, 0, stream>>>(Ctx, Wot, bo, out);
}

// Round 13
// 253.618 us; speedup vs baseline: 1.0753x; 1.0753x over previous
//
#include <hip/hip_runtime.h>

// Problem constants
#define BATCH   2
#define S_LEN   4096
#define D_MODEL 768
#define NH      12
#define HDIM    64
#define MROWS   (BATCH * S_LEN)   // 8192
#define QBLK    128
#define KVBLK   64
#define NT      (S_LEN / KVBLK)   // 64
#define NXB     (MROWS * D_MODEL / 4 / 256)   // 6144 conv blocks
#define NTW     2304                          // 24*24*4 trans_w blocks
#define LOG2E   1.4426950408889634f

typedef float f32x4  __attribute__((ext_vector_type(4)));
typedef float f32x16 __attribute__((ext_vector_type(16)));
typedef short bf16x8 __attribute__((ext_vector_type(8)));

#if __has_builtin(__builtin_amdgcn_exp2f)
#define EXP2(x) __builtin_amdgcn_exp2f(x)
#else
#define EXP2(x) exp2f(x)
#endif

static __device__ __forceinline__ unsigned short f2bf(float f) {
  union { float f; unsigned u; } v; v.f = f;
  unsigned r = v.u + 0x7fffu + ((v.u >> 16) & 1u);
  return (unsigned short)(r >> 16);
}

static __device__ __forceinline__ unsigned cvtpk(float lo, float hi) {
  unsigned r;
  asm("v_cvt_pk_bf16_f32 %0, %1, %2" : "=v"(r) : "v"(lo), "v"(hi));
  return r;
}

// async global->LDS, 16B per lane (dest must be wave-uniform base + lane*16)
typedef __attribute__((address_space(1))) const unsigned int as1_cuint;
typedef __attribute__((address_space(3))) unsigned int as3_uint;
static __device__ __forceinline__ void gload_lds16(const unsigned short* g,
                                                   unsigned short* l) {
  __builtin_amdgcn_global_load_lds((as1_cuint*)g, (as3_uint*)l, 16, 0, 0);
}

// Build PV A-fragment from 8 P regs (layout verified R2).
template <int BASE>
static __device__ __forceinline__ bf16x8 pack_frag(const f32x16& s) {
  unsigned a0 = cvtpk(s[BASE + 0], s[BASE + 1]);
  unsigned b0 = cvtpk(s[BASE + 4], s[BASE + 5]);
  asm("v_permlane32_swap_b32 %0, %1" : "+v"(a0), "+v"(b0));
  unsigned a1 = cvtpk(s[BASE + 2], s[BASE + 3]);
  unsigned b1 = cvtpk(s[BASE + 6], s[BASE + 7]);
  asm("v_permlane32_swap_b32 %0, %1" : "+v"(a1), "+v"(b1));
  union { unsigned w[4]; bf16x8 v; } u;
  u.w[0] = a0; u.w[1] = a1; u.w[2] = b0; u.w[3] = b1;
  return u.v;
}

#define Z16 {0.f,0.f,0.f,0.f,0.f,0.f,0.f,0.f,0.f,0.f,0.f,0.f,0.f,0.f,0.f,0.f}

// ---------------------------------------------------------------- fused prepass
// blocks [0, NXB)          : X -> bf16 (conv)
// block  NXB               : mask -> madd + allones flag
// blocks (NXB, NXB+NTW]    : W[k][n] fp32 -> T[n][k] bf16 (transpose), 4 weights
__global__ __launch_bounds__(256) void prepass(
    const float* __restrict__ X, unsigned short* __restrict__ Xb,
    const float* __restrict__ mask, float* __restrict__ madd, int* __restrict__ flag,
    const float* __restrict__ W0, const float* __restrict__ W1,
    const float* __restrict__ W2, const float* __restrict__ W3,
    unsigned short* __restrict__ T0, unsigned short* __restrict__ T1,
    unsigned short* __restrict__ T2, unsigned short* __restrict__ T3) {
  __shared__ float tile[32][33];
  __shared__ int ok[4];
  int bid = blockIdx.x;
  int t = threadIdx.x;
  if (bid < NXB) {
    int i = bid * 256 + t;
    float4 v = ((const float4*)X)[i];
    ushort4 o;
    o.x = f2bf(v.x); o.y = f2bf(v.y); o.z = f2bf(v.z); o.w = f2bf(v.w);
    ((ushort4*)Xb)[i] = o;
    return;
  }
  if (bid == NXB) {
    int all1 = 1;
    #pragma unroll
    for (int i = 0; i < MROWS / 256; ++i) {
      int idx = i * 256 + t;
      float m = mask[idx];
      madd[idx] = (-1e6f * LOG2E) * (1.0f - m);
      all1 &= (m == 1.0f);
    }
    all1 = __all(all1) ? 1 : 0;
    if ((t & 63) == 0) ok[t >> 6] = all1;
    __syncthreads();
    if (t == 0) *flag = ok[0] & ok[1] & ok[2] & ok[3];
    return;
  }
  // trans_w region
  int w2 = bid - (NXB + 1);          // 0..2303
  int zz = w2 / 576;
  int r = w2 - zz * 576;
  int bxi = r % 24, byi = r / 24;
  const float* W; unsigned short* T;
  if (zz == 0) { W = W0; T = T0; }
  else if (zz == 1) { W = W1; T = T1; }
  else if (zz == 2) { W = W2; T = T2; }
  else { W = W3; T = T3; }
  int tx = t & 31, ty = t >> 5;
  int bx = bxi * 32, by = byi * 32;
  #pragma unroll
  for (int i = ty; i < 32; i += 8) tile[i][tx] = W[(size_t)(by + i) * D_MODEL + bx + tx];
  __syncthreads();
  #pragma unroll
  for (int i = ty; i < 32; i += 8)
    T[(size_t)(bx + i) * D_MODEL + by + tx] = f2bf(tile[tx][i]);
}

// ---------------------------------------------------------------- QKV GEMM
// m97 structure: 128x128 tile, 4 waves x (64x64), BK=64, global_load_lds x16.
__global__ __launch_bounds__(256) void qkv_gemm(
    const unsigned short* __restrict__ Xb,
    const unsigned short* __restrict__ Wqt, const unsigned short* __restrict__ Wkt,
    const unsigned short* __restrict__ Wvt,
    const float* __restrict__ bq, const float* __restrict__ bk, const float* __restrict__ bv,
    unsigned short* __restrict__ Qo, unsigned short* __restrict__ Ko,
    unsigned short* __restrict__ Vto) {
  __shared__ unsigned short As[128 * 64];   // linear [128][64]
  __shared__ unsigned short Bs[128 * 64];
  int zz = blockIdx.z;
  const unsigned short* Wt = zz == 0 ? Wqt : (zz == 1 ? Wkt : Wvt);
  const float* bias = zz == 0 ? bq : (zz == 1 ? bk : bv);
  int tid = threadIdx.x;
  int w = tid >> 6, lane = tid & 63, lr = lane & 15, lg = lane >> 4;
  int wr = w >> 1, wc = w & 1;
  int mb = blockIdx.x * 128, nb = blockIdx.y * 128;
  const unsigned short* Ag = Xb + (size_t)(mb + (tid >> 3)) * D_MODEL + (tid & 7) * 8;
  const unsigned short* Bg = Wt + (size_t)(nb + (tid >> 3)) * D_MODEL + (tid & 7) * 8;
  unsigned short* Al = As + (size_t)tid * 8;
  unsigned short* Bl = Bs + (size_t)tid * 8;
  f32x4 acc[4][4];
  #pragma unroll
  for (int m = 0; m < 4; ++m)
    #pragma unroll
    for (int n = 0; n < 4; ++n) acc[m][n] = (f32x4){0.f, 0.f, 0.f, 0.f};
  for (int kb = 0; kb < D_MODEL / 64; ++kb) {
    __syncthreads();
    #pragma unroll
    for (int i = 0; i < 4; ++i) {
      gload_lds16(Ag + (size_t)(i * 32) * D_MODEL + kb * 64, Al + i * 2048);
      gload_lds16(Bg + (size_t)(i * 32) * D_MODEL + kb * 64, Bl + i * 2048);
    }
    __syncthreads();   // compiler inserts vmcnt(0) drain
    #pragma unroll
    for (int kk = 0; kk < 2; ++kk) {
      bf16x8 af[4], bfv[4];
      #pragma unroll
      for (int m = 0; m < 4; ++m)
        af[m] = *(const bf16x8*)(As + (wr * 64 + m * 16 + lr) * 64 + kk * 32 + lg * 8);
      #pragma unroll
      for (int n = 0; n < 4; ++n)
        bfv[n] = *(const bf16x8*)(Bs + (wc * 64 + n * 16 + lr) * 64 + kk * 32 + lg * 8);
      #pragma unroll
      for (int m = 0; m < 4; ++m)
        #pragma unroll
        for (int n = 0; n < 4; ++n)
          acc[m][n] = __builtin_amdgcn_mfma_f32_16x16x32_bf16(af[m], bfv[n], acc[m][n], 0, 0, 0);
    }
  }
  #pragma unroll
  for (int n = 0; n < 4; ++n) {
    int nc = nb + wc * 64 + n * 16 + lr;
    float bia = bias[nc];
    int h = nc >> 6, hd = nc & 63;
    #pragma unroll
    for (int m = 0; m < 4; ++m) {
      #pragma unroll
      for (int r = 0; r < 4; ++r) {
        int mr = mb + wr * 64 + m * 16 + lg * 4 + r;
        int b = mr >> 12, s = mr & 4095;
        float val = acc[m][n][r] + bia;
        if (zz == 0)
          Qo[((size_t)(b * NH + h) * S_LEN + s) * HDIM + hd] = f2bf(val * 0.125f * LOG2E);
        else if (zz == 1)
          Ko[((size_t)(b * NH + h) * S_LEN + s) * HDIM + hd] = f2bf(val);
        else
          Vto[((size_t)(b * NH + h) * HDIM + hd) * S_LEN + s] = f2bf(val);
      }
    }
  }
}

// ---------------------------------------------------------------- attention
// R6/R11-verified: 4 waves x 32 q-rows (QBLK=128). Double-buffered LDS K/V,
// async-split staging (reg roundtrip), ONE barrier per KV tile. XCD chunk
// swizzle. No max tracking (bounded scores; masked -> exp2(-1.4e6)=0).
__global__ __launch_bounds__(256) void attn_kernel(
    const unsigned short* __restrict__ Q, const unsigned short* __restrict__ K,
    const unsigned short* __restrict__ Vt, const float* __restrict__ madd,
    const int* __restrict__ allones_p, unsigned short* __restrict__ Ctx) {
  __shared__ unsigned short Ks[2][64][72];
  __shared__ unsigned short Vs[2][64][72];
  int lin = blockIdx.x;                       // 0..767
  int wg = (lin & 7) * 96 + (lin >> 3);       // bijective (768 % 8 == 0)
  int qb = wg & 31, bh = wg >> 5;
  int b = bh / NH, h = bh % NH;
  int tid = threadIdx.x;
  int w = tid >> 6, lane = tid & 63;
  int lq = lane & 31, hi = lane >> 5;
  const unsigned short* Qb = Q + (size_t)bh * S_LEN * HDIM;
  const unsigned short* Kb = K + (size_t)bh * S_LEN * HDIM;
  const unsigned short* Vb = Vt + (size_t)bh * HDIM * S_LEN;
  const float* maddb = madd + (size_t)b * S_LEN;
  const int allones = *allones_p;

  int qrow = qb * QBLK + w * 32 + lq;
  bf16x8 qf0 = *(const bf16x8*)(Qb + (size_t)qrow * HDIM + 0 * 16 + hi * 8);
  bf16x8 qf1 = *(const bf16x8*)(Qb + (size_t)qrow * HDIM + 1 * 16 + hi * 8);
  bf16x8 qf2 = *(const bf16x8*)(Qb + (size_t)qrow * HDIM + 2 * 16 + hi * 8);
  bf16x8 qf3 = *(const bf16x8*)(Qb + (size_t)qrow * HDIM + 3 * 16 + hi * 8);

  f32x16 acc0 = Z16, acc1 = Z16;
  float l_run = 0.f;

  int srow = tid >> 3, sseg = (tid & 7) * 8;
  uint4 ka, kc, va, vc;   // staging regs (next tile)

  // prologue: stage tile 0
  ka = *(const uint4*)(Kb + (size_t)srow * HDIM + sseg);
  kc = *(const uint4*)(Kb + (size_t)(srow + 32) * HDIM + sseg);
  va = *(const uint4*)(Vb + (size_t)srow * S_LEN + sseg);
  vc = *(const uint4*)(Vb + (size_t)(srow + 32) * S_LEN + sseg);
  *(uint4*)&Ks[0][srow][sseg]      = ka;
  *(uint4*)&Ks[0][srow + 32][sseg] = kc;
  *(uint4*)&Vs[0][srow][sseg]      = va;
  *(uint4*)&Vs[0][srow + 32][sseg] = vc;
  __syncthreads();

  for (int t = 0; t < NT; ++t) {
    int cur = t & 1;
    int kbase = t * KVBLK;
    // ---- issue next tile's global loads EARLY (latency hides under compute)
    if (t + 1 < NT) {
      int nb2 = kbase + KVBLK;
      ka = *(const uint4*)(Kb + (size_t)(nb2 + srow) * HDIM + sseg);
      kc = *(const uint4*)(Kb + (size_t)(nb2 + srow + 32) * HDIM + sseg);
      va = *(const uint4*)(Vb + (size_t)srow * S_LEN + nb2 + sseg);
      vc = *(const uint4*)(Vb + (size_t)(srow + 32) * S_LEN + nb2 + sseg);
    }
    // ---- S^T[k][q] = K . Q^T
    f32x16 s0 = Z16, s1 = Z16;
    #pragma unroll
    for (int c = 0; c < 4; ++c) {
      bf16x8 kf0 = *(const bf16x8*)(&Ks[cur][lq][c * 16 + hi * 8]);
      bf16x8 kf1 = *(const bf16x8*)(&Ks[cur][32 + lq][c * 16 + hi * 8]);
      bf16x8 qf = c == 0 ? qf0 : (c == 1 ? qf1 : (c == 2 ? qf2 : qf3));
      s0 = __builtin_amdgcn_mfma_f32_32x32x16_bf16(kf0, qf, s0, 0, 0, 0);
      s1 = __builtin_amdgcn_mfma_f32_32x32x16_bf16(kf1, qf, s1, 0, 0, 0);
    }
    // ---- mask (skipped when all-ones; uniform branch)
    if (!allones) {
      #pragma unroll
      for (int g = 0; g < 4; ++g) {
        float4 m0 = *(const float4*)(maddb + kbase + g * 8 + hi * 4);
        float4 m1 = *(const float4*)(maddb + kbase + 32 + g * 8 + hi * 4);
        s0[g * 4 + 0] += m0.x; s0[g * 4 + 1] += m0.y;
        s0[g * 4 + 2] += m0.z; s0[g * 4 + 3] += m0.w;
        s1[g * 4 + 0] += m1.x; s1[g * 4 + 1] += m1.y;
        s1[g * 4 + 2] += m1.z; s1[g * 4 + 3] += m1.w;
      }
    }
    // ---- p = exp2(s), row sums (no max subtraction)
    float psA = 0.f, psB = 0.f, psC = 0.f, psD = 0.f;
    #pragma unroll
    for (int r = 0; r < 4; ++r) {
      s0[r]      = EXP2(s0[r]);      psA += s0[r];
      s0[r + 4]  = EXP2(s0[r + 4]);  psB += s0[r + 4];
      s0[r + 8]  = EXP2(s0[r + 8]);  psC += s0[r + 8];
      s0[r + 12] = EXP2(s0[r + 12]); psD += s0[r + 12];
    }
    #pragma unroll
    for (int r = 0; r < 4; ++r) {
      s1[r]      = EXP2(s1[r]);      psA += s1[r];
      s1[r + 4]  = EXP2(s1[r + 4]);  psB += s1[r + 4];
      s1[r + 8]  = EXP2(s1[r + 8]);  psC += s1[r + 8];
      s1[r + 12] = EXP2(s1[r + 12]); psD += s1[r + 12];
    }
    float psum = (psA + psB) + (psC + psD);
    psum += __shfl_xor(psum, 32, 64);
    l_run += psum;
    // ---- pack P and PV
    bf16x8 pa0 = pack_frag<0>(s0);
    bf16x8 pa1 = pack_frag<8>(s0);
    bf16x8 pa2 = pack_frag<0>(s1);
    bf16x8 pa3 = pack_frag<8>(s1);
    #pragma unroll
    for (int c = 0; c < 4; ++c) {
      bf16x8 pa = c == 0 ? pa0 : (c == 1 ? pa1 : (c == 2 ? pa2 : pa3));
      bf16x8 vf0 = *(const bf16x8*)(&Vs[cur][lq][c * 16 + hi * 8]);
      bf16x8 vf1 = *(const bf16x8*)(&Vs[cur][32 + lq][c * 16 + hi * 8]);
      acc0 = __builtin_amdgcn_mfma_f32_32x32x16_bf16(pa, vf0, acc0, 0, 0, 0);
      acc1 = __builtin_amdgcn_mfma_f32_32x32x16_bf16(pa, vf1, acc1, 0, 0, 0);
    }
    // ---- write next tile to the other buffer; one barrier per tile
    if (t + 1 < NT) {
      int nxt = cur ^ 1;
      *(uint4*)&Ks[nxt][srow][sseg]      = ka;
      *(uint4*)&Ks[nxt][srow + 32][sseg] = kc;
      *(uint4*)&Vs[nxt][srow][sseg]      = va;
      *(uint4*)&Vs[nxt][srow + 32][sseg] = vc;
      __syncthreads();
    }
  }
  // ---- epilogue
  #pragma unroll
  for (int r = 0; r < 16; ++r) {
    int qr = (r & 3) + 8 * (r >> 2) + 4 * hi;
    float lv = __shfl(l_run, qr, 64);
    float rl = 1.0f / lv;
    int qglob = qb * QBLK + w * 32 + qr;
    size_t base = ((size_t)(b * S_LEN + qglob)) * D_MODEL + h * HDIM;
    Ctx[base + lq]      = f2bf(acc0[r] * rl);
    Ctx[base + 32 + lq] = f2bf(acc1[r] * rl);
  }
}

// ---------------------------------------------------------------- out proj
__global__ __launch_bounds__(256) void out_gemm(
    const unsigned short* __restrict__ Ctx, const unsigned short* __restrict__ Wot,
    const float* __restrict__ bo, float* __restrict__ Out) {
  __shared__ unsigned short As[128 * 64];
  __shared__ unsigned short Bs[128 * 64];
  int tid = threadIdx.x;
  int w = tid >> 6, lane = tid & 63, lr = lane & 15, lg = lane >> 4;
  int wr = w >> 1, wc = w & 1;
  int mb = blockIdx.x * 128, nb = blockIdx.y * 128;
  const unsigned short* Ag = Ctx + (size_t)(mb + (tid >> 3)) * D_MODEL + (tid & 7) * 8;
  const unsigned short* Bg = Wot + (size_t)(nb + (tid >> 3)) * D_MODEL + (tid & 7) * 8;
  unsigned short* Al = As + (size_t)tid * 8;
  unsigned short* Bl = Bs + (size_t)tid * 8;
  f32x4 acc[4][4];
  #pragma unroll
  for (int m = 0; m < 4; ++m)
    #pragma unroll
    for (int n = 0; n < 4; ++n) acc[m][n] = (f32x4){0.f, 0.f, 0.f, 0.f};
  for (int kb = 0; kb < D_MODEL / 64; ++kb) {
    __syncthreads();
    #pragma unroll
    for (int i = 0; i < 4; ++i) {
      gload_lds16(Ag + (size_t)(i * 32) * D_MODEL + kb * 64, Al + i * 2048);
      gload_lds16(Bg + (size_t)(i * 32) * D_MODEL + kb * 64, Bl + i * 2048);
    }
    __syncthreads();
    #pragma unroll
    for (int kk = 0; kk < 2; ++kk) {
      bf16x8 af[4], bfv[4];
      #pragma unroll
      for (int m = 0; m < 4; ++m)
        af[m] = *(const bf16x8*)(As + (wr * 64 + m * 16 + lr) * 64 + kk * 32 + lg * 8);
      #pragma unroll
      for (int n = 0; n < 4; ++n)
        bfv[n] = *(const bf16x8*)(Bs + (wc * 64 + n * 16 + lr) * 64 + kk * 32 + lg * 8);
      #pragma unroll
      for (int m = 0; m < 4; ++m)
        #pragma unroll
        for (int n = 0; n < 4; ++n)
          acc[m][n] = __builtin_amdgcn_mfma_f32_16x16x32_bf16(af[m], bfv[n], acc[m][n], 0, 0, 0);
    }
  }
  #pragma unroll
  for (int n = 0; n < 4; ++n) {
    int nc = nb + wc * 64 + n * 16 + lr;
    float bia = bo[nc];
    #pragma unroll
    for (int m = 0; m < 4; ++m) {
      #pragma unroll
      for (int r = 0; r < 4; ++r) {
        int mr = mb + wr * 64 + m * 16 + lg * 4 + r;
        Out[(size_t)mr * D_MODEL + nc] = acc[m][n][r] + bia;
      }
    }
  }
}

// ---------------------------------------------------------------- launch

extern "C" void kernel_launch(void* const* d_in, const int* in_sizes, int n_in,
                              void* d_out, int out_size, void* d_ws, size_t ws_size,
                              hipStream_t stream) {
  const float* X    = (const float*)d_in[0];
  const float* mask = (const float*)d_in[1];
  const float* Wq   = (const float*)d_in[2];
  const float* bq   = (const float*)d_in[3];
  const float* Wk   = (const float*)d_in[4];
  const float* bk   = (const float*)d_in[5];
  const float* Wv   = (const float*)d_in[6];
  const float* bv   = (const float*)d_in[7];
  const float* Wo   = (const float*)d_in[8];
  const float* bo   = (const float*)d_in[9];
  float* out = (float*)d_out;
  char* ws = (char*)d_ws;

  const size_t XB_OFF   = 0;
  const size_t WQT_OFF  = 12582912;
  const size_t WKT_OFF  = WQT_OFF + 1179648;
  const size_t WVT_OFF  = WKT_OFF + 1179648;
  const size_t WOT_OFF  = WVT_OFF + 1179648;
  const size_t Q_OFF    = WOT_OFF + 1179648;
  const size_t K_OFF    = Q_OFF + 12582912;
  const size_t VT_OFF   = K_OFF + 12582912;
  const size_t CTX_OFF  = VT_OFF + 12582912;
  const size_t MADD_OFF = CTX_OFF + 12582912;
  const size_t FLAG_OFF = MADD_OFF + MROWS * 4;

  unsigned short* Xb  = (unsigned short*)(ws + XB_OFF);
  unsigned short* Wqt = (unsigned short*)(ws + WQT_OFF);
  unsigned short* Wkt = (unsigned short*)(ws + WKT_OFF);
  unsigned short* Wvt = (unsigned short*)(ws + WVT_OFF);
  unsigned short* Wot = (unsigned short*)(ws + WOT_OFF);
  unsigned short* Qw  = (unsigned short*)(ws + Q_OFF);
  unsigned short* Kw  = (unsigned short*)(ws + K_OFF);
  unsigned short* Vtw = (unsigned short*)(ws + VT_OFF);
  unsigned short* Ctx = (unsigned short*)(ws + CTX_OFF);
  float* madd = (float*)(ws + MADD_OFF);
  int* flag   = (int*)(ws + FLAG_OFF);

  prepass<<<dim3(NXB + 1 + NTW), 256, 0, stream>>>(
      X, Xb, mask, madd, flag, Wq, Wk, Wv, Wo, Wqt, Wkt, Wvt, Wot);
  qkv_gemm<<<dim3(MROWS / 128, D_MODEL / 128, 3), 256, 0, stream>>>(
      Xb, Wqt, Wkt, Wvt, bq, bk, bv, Qw, Kw, Vtw);
  attn_kernel<<<dim3((S_LEN / QBLK) * (BATCH * NH)), 256, 0, stream>>>(
      Qw, Kw, Vtw, madd, flag, Ctx);
  out_gemm<<<dim3(MROWS / 128, D_MODEL / 128), 256, 0, stream>>>(Ctx, Wot, bo, out);
}